// Round 4
// baseline (334.143 us; speedup 1.0000x reference)
//
#include <hip/hip_runtime.h>
#include <math.h>

// B=8, N=256, D=128. score[b,i,j] = <val_i,val_j> + <dep_ij, dep_ji> is
// symmetric in (i,j); out = exp(score)*adj with adj ~5% dense + diagonal.
// R4: two-phase stream compaction. Phase A scans adj (coalesced), writes
// exact zeros for dead pairs, compacts live pair-ids into d_ws (one atomic
// per block). Phase B gathers dep rows only for live pairs with DENSE
// half-waves (8 gathers each, unrolled) so HBM latency overlaps.

#define BB 8
#define NN 256
#define DD 128

constexpr float EPS = 1e-10f;
constexpr float INV_SQRT_D = 0.08838834764831845f; // 1/sqrt(128)

constexpr int RECT_H = NN / 2;                     // 128
constexpr int RECT_W = NN + 1;                     // 257
constexpr int PAIRS_PER_BATCH = RECT_H * RECT_W;   // 32896 = N(N+1)/2
constexpr int TOTAL_PAIRS = BB * PAIRS_PER_BATCH;  // 263168

__device__ __forceinline__ void decode_pair(int pair, int& b, int& i, int& j) {
    b = pair / PAIRS_PER_BATCH;
    const int t = pair - b * PAIRS_PER_BATCH;
    const int r = t / RECT_W;
    const int c = t - r * RECT_W;
    if (c < NN - r) { i = r;          j = r + c; }
    else            { i = NN - 1 - r; j = c - 1; }
}

__global__ void init_kernel(unsigned int* cnt) {
    if (threadIdx.x == 0) *cnt = 0u;
}

__global__ __launch_bounds__(256) void scan_kernel(
    const float* __restrict__ adj, float* __restrict__ out,
    unsigned int* __restrict__ cnt, int* __restrict__ list)
{
    const int pair = blockIdx.x * 256 + threadIdx.x;
    int b, i, j;
    decode_pair(pair, b, i, j);
    const size_t base = (size_t)b * NN * NN;
    const size_t ij = base + (size_t)i * NN + j;
    const size_t ji = base + (size_t)j * NN + i;
    const float aij = adj[ij];
    const float aji = adj[ji];
    const bool active = (aij != 0.0f) || (aji != 0.0f);
    if (!active) { out[ij] = 0.0f; out[ji] = 0.0f; }

    // block-aggregated compaction: 1 atomic per block
    const unsigned long long m = __ballot(active);
    const int lane = threadIdx.x & 63;
    const int wid  = threadIdx.x >> 6;
    __shared__ unsigned int wcnt[4];
    __shared__ unsigned int wbase[4];
    if (lane == 0) wcnt[wid] = (unsigned int)__popcll(m);
    __syncthreads();
    if (threadIdx.x == 0) {
        const unsigned int tot = wcnt[0] + wcnt[1] + wcnt[2] + wcnt[3];
        const unsigned int b0 = tot ? atomicAdd(cnt, tot) : 0u;
        wbase[0] = b0;
        wbase[1] = b0 + wcnt[0];
        wbase[2] = b0 + wcnt[0] + wcnt[1];
        wbase[3] = b0 + wcnt[0] + wcnt[1] + wcnt[2];
    }
    __syncthreads();
    if (active) {
        const unsigned long long below = m & ((1ull << lane) - 1ull);
        list[wbase[wid] + (unsigned int)__popcll(below)] = pair;
    }
}

constexpr int B_ITERS = 8;
constexpr int B_PAIRS_PER_BLOCK = 8 * B_ITERS;             // 64
constexpr int B_GRID = TOTAL_PAIRS / B_PAIRS_PER_BLOCK;    // 4112 (worst case)

__global__ __launch_bounds__(256) void gather_kernel(
    const float* __restrict__ val, const float* __restrict__ dep,
    const float* __restrict__ adj, const unsigned int* __restrict__ cnt,
    const int* __restrict__ list, float* __restrict__ out)
{
    const unsigned int n = *cnt;
    const unsigned int base_idx = blockIdx.x * B_PAIRS_PER_BLOCK;
    if (base_idx >= n) return;   // dead block, retire immediately

    const int hw   = threadIdx.x >> 5;
    const int lane = threadIdx.x & 31;

    #pragma unroll
    for (int it = 0; it < B_ITERS; ++it) {
        const unsigned int idx = base_idx + it * 8 + hw;
        if (idx >= n) continue;
        const int pair = list[idx];
        int b, i, j;
        decode_pair(pair, b, i, j);
        const size_t base = (size_t)b * NN * NN;
        const size_t ij = base + (size_t)i * NN + j;
        const size_t ji = base + (size_t)j * NN + i;

        const float4 a  = ((const float4*)(dep + ij * DD))[lane];
        const float4 bt = ((const float4*)(dep + ji * DD))[lane];
        const float4 x  = ((const float4*)(val + ((size_t)b * NN + i) * DD))[lane];
        const float4 y  = ((const float4*)(val + ((size_t)b * NN + j) * DD))[lane];

        float p = a.x * bt.x + a.y * bt.y + a.z * bt.z + a.w * bt.w
                + x.x * y.x  + x.y * y.y  + x.z * y.z  + x.w * y.w;

        #pragma unroll
        for (int mk = 16; mk >= 1; mk >>= 1) p += __shfl_xor(p, mk, 64);

        if (lane == 0) {
            const float e = __expf(p * INV_SQRT_D);
            out[ij] = e * adj[ij];
            out[ji] = e * adj[ji];   // i==j: same addr, same value, same thread
        }
    }
}

__global__ __launch_bounds__(256) void norm_kernel(float* __restrict__ out)
{
    const int row = blockIdx.x;              // b*N + i
    const int tid = threadIdx.x;             // j
    const size_t idx = (size_t)row * NN + tid;
    const float x = out[idx];

    float s = x;
    #pragma unroll
    for (int m = 32; m >= 1; m >>= 1) s += __shfl_xor(s, m, 64);

    __shared__ float ws[4];
    __shared__ float denom_s;
    const int wid = tid >> 6;
    if ((tid & 63) == 0) ws[wid] = s;
    __syncthreads();
    if (tid == 0) denom_s = ws[0] + ws[1] + ws[2] + ws[3] + EPS;
    __syncthreads();

    out[idx] = x / denom_s;
}

extern "C" void kernel_launch(void* const* d_in, const int* in_sizes, int n_in,
                              void* d_out, int out_size, void* d_ws, size_t ws_size,
                              hipStream_t stream) {
    const float* val = (const float*)d_in[0];
    const float* dep = (const float*)d_in[1];
    const float* adj = (const float*)d_in[2];
    float* out = (float*)d_out;

    unsigned int* cnt = (unsigned int*)d_ws;          // 4 B counter
    int* list = (int*)((char*)d_ws + 16);             // pair-id list (~1 MB)

    static_assert(TOTAL_PAIRS % 256 == 0, "scan grid exact");
    init_kernel<<<1, 64, 0, stream>>>(cnt);
    scan_kernel<<<TOTAL_PAIRS / 256, 256, 0, stream>>>(adj, out, cnt, list);
    gather_kernel<<<B_GRID, 256, 0, stream>>>(val, dep, adj, cnt, list, out);
    norm_kernel<<<BB * NN, 256, 0, stream>>>(out);
}

// Round 5
// 306.586 us; speedup vs baseline: 1.0899x; 1.0899x over previous
//
#include <hip/hip_runtime.h>
#include <math.h>

// B=8, N=256, D=128. out[b,i,j] = exp(score[b,i,j])*adj[b,i,j] / rowsum,
// score = (<val_i,val_j> + <dep_ij,dep_ji>)/sqrt(D). adj ~5% dense + diag.
// R5: fully fused, one block per output row (b,i). Coalesced adj read ->
// in-block compaction of active j's (adj[i,j]!=0) -> dense half-wave dep
// gathers (only ~29 MB of dep touched) -> exp -> block row-sum -> coalesced
// row store. No scattered stores, no norm pass, no global compaction.

#define BB 8
#define NN 256
#define DD 128

constexpr float EPS = 1e-10f;
constexpr float INV_SQRT_D = 0.08838834764831845f; // 1/sqrt(128)

__global__ __launch_bounds__(256) void row_kernel(
    const float* __restrict__ val,   // [B,N,D]
    const float* __restrict__ dep,   // [B,N,N,D]
    const float* __restrict__ adj,   // [B,N,N]
    float* __restrict__ out)         // [B,N,N]
{
    const int row = blockIdx.x;          // b*N + i
    const int b   = row >> 8;
    const int i   = row & 255;
    const int tid = threadIdx.x;         // candidate j

    __shared__ int   lst[NN];
    __shared__ float aval[NN];
    __shared__ float escore[NN];
    __shared__ unsigned int wcnt[4];
    __shared__ float wsum[4];

    // ---- phase 1: coalesced adj row read + in-block compaction ----
    const float a = adj[(size_t)row * NN + tid];
    const bool active = (a != 0.0f);
    const unsigned long long m = __ballot(active);
    const int lane64 = tid & 63;
    const int wid    = tid >> 6;
    if (lane64 == 0) wcnt[wid] = (unsigned int)__popcll(m);
    escore[tid] = 0.0f;
    __syncthreads();

    const unsigned int n0 = wcnt[0], n1 = wcnt[1], n2 = wcnt[2], n3 = wcnt[3];
    const int nact = (int)(n0 + n1 + n2 + n3);
    unsigned int base = 0;
    if (wid > 0) base += n0;
    if (wid > 1) base += n1;
    if (wid > 2) base += n2;
    if (active) {
        const unsigned long long below = m & ((1ull << lane64) - 1ull);
        const int pos = (int)(base + (unsigned int)__popcll(below));
        lst[pos]  = tid;
        aval[pos] = a;
    }
    __syncthreads();

    // ---- phase 2: dense gathers over active entries ----
    const int hw   = tid >> 5;           // 8 half-waves
    const int lane = tid & 31;
    const float4 xv = ((const float4*)(val + ((size_t)b * NN + i) * DD))[lane];

    for (int k = hw; k < nact; k += 8) {
        const int j = lst[k];
        const size_t bij = (((size_t)b * NN + i) * NN + j) * DD;
        const size_t bji = (((size_t)b * NN + j) * NN + i) * DD;
        const float4 a4 = ((const float4*)(dep + bij))[lane];
        const float4 b4 = ((const float4*)(dep + bji))[lane];
        const float4 yv = ((const float4*)(val + ((size_t)b * NN + j) * DD))[lane];

        float p = a4.x * b4.x + a4.y * b4.y + a4.z * b4.z + a4.w * b4.w
                + xv.x * yv.x + xv.y * yv.y + xv.z * yv.z + xv.w * yv.w;

        #pragma unroll
        for (int mk = 16; mk >= 1; mk >>= 1) p += __shfl_xor(p, mk, 64);

        if (lane == 0) escore[j] = __expf(p * INV_SQRT_D) * aval[k];
    }
    __syncthreads();

    // ---- phase 3: row normalize + coalesced store ----
    const float x = escore[tid];
    float s = x;
    #pragma unroll
    for (int mk = 32; mk >= 1; mk >>= 1) s += __shfl_xor(s, mk, 64);
    if (lane64 == 0) wsum[wid] = s;
    __syncthreads();
    const float denom = wsum[0] + wsum[1] + wsum[2] + wsum[3] + EPS;
    out[(size_t)row * NN + tid] = x / denom;
}

extern "C" void kernel_launch(void* const* d_in, const int* in_sizes, int n_in,
                              void* d_out, int out_size, void* d_ws, size_t ws_size,
                              hipStream_t stream) {
    const float* val = (const float*)d_in[0];
    const float* dep = (const float*)d_in[1];
    const float* adj = (const float*)d_in[2];
    float* out = (float*)d_out;

    row_kernel<<<BB * NN, 256, 0, stream>>>(val, dep, adj, out);
}

// Round 6
// 306.102 us; speedup vs baseline: 1.0916x; 1.0016x over previous
//
#include <hip/hip_runtime.h>
#include <math.h>

// B=8, N=256, D=128. out[b,i,j] = exp(score[b,i,j])*adj[b,i,j] / rowsum,
// score = (<val_i,val_j> + <dep_ij,dep_ji>)/sqrt(D). adj ~5% dense + diag.
// R6: row-fused kernel (one block per (b,i) row) with 16-LANE gather groups:
// 16 groups/block -> typical row (nact~14) finishes all dep gathers in ONE
// memory round trip; each group issues 6 independent dwordx4 loads (high MLP).
// Coalesced adj read -> in-block compaction -> dense gathers -> exp ->
// fused row-normalize -> coalesced row store. Only ~33 MB touched.

#define BB 8
#define NN 256
#define DD 128

constexpr float EPS = 1e-10f;
constexpr float INV_SQRT_D = 0.08838834764831845f; // 1/sqrt(128)

__global__ __launch_bounds__(256) void row_kernel(
    const float* __restrict__ val,   // [B,N,D]
    const float* __restrict__ dep,   // [B,N,N,D]
    const float* __restrict__ adj,   // [B,N,N]
    float* __restrict__ out)         // [B,N,N]
{
    const int row = blockIdx.x;          // b*N + i
    const int b   = row >> 8;
    const int i   = row & 255;
    const int tid = threadIdx.x;         // candidate j

    __shared__ int   lst[NN];
    __shared__ float aval[NN];
    __shared__ float escore[NN];
    __shared__ unsigned int wcnt[4];
    __shared__ float wsum[4];

    // ---- phase 1: coalesced adj row read + in-block compaction ----
    const float a = adj[(size_t)row * NN + tid];
    const bool active = (a != 0.0f);
    const unsigned long long m = __ballot(active);
    const int lane64 = tid & 63;
    const int wid    = tid >> 6;
    if (lane64 == 0) wcnt[wid] = (unsigned int)__popcll(m);
    escore[tid] = 0.0f;
    __syncthreads();

    const unsigned int n0 = wcnt[0], n1 = wcnt[1], n2 = wcnt[2], n3 = wcnt[3];
    const int nact = (int)(n0 + n1 + n2 + n3);
    unsigned int base = 0;
    if (wid > 0) base += n0;
    if (wid > 1) base += n1;
    if (wid > 2) base += n2;
    if (active) {
        const unsigned long long below = m & ((1ull << lane64) - 1ull);
        const int pos = (int)(base + (unsigned int)__popcll(below));
        lst[pos]  = tid;
        aval[pos] = a;
    }
    __syncthreads();

    // ---- phase 2: dense gathers, 16-lane groups, 16 groups/block ----
    const int g      = tid >> 4;         // group id 0..15
    const int lane16 = tid & 15;
    // lane l covers d = l*32B..: float4 indices 2l, 2l+1
    const float4* vi = (const float4*)(val + ((size_t)b * NN + i) * DD);
    const float4 x0 = vi[2 * lane16];
    const float4 x1 = vi[2 * lane16 + 1];

    for (int k = g; k < nact; k += 16) {
        const int j = lst[k];
        const float4* dij = (const float4*)(dep + (((size_t)b * NN + i) * NN + j) * DD);
        const float4* dji = (const float4*)(dep + (((size_t)b * NN + j) * NN + i) * DD);
        const float4* vj  = (const float4*)(val + ((size_t)b * NN + j) * DD);
        const float4 a0 = dij[2 * lane16];
        const float4 a1 = dij[2 * lane16 + 1];
        const float4 b0 = dji[2 * lane16];
        const float4 b1 = dji[2 * lane16 + 1];
        const float4 y0 = vj[2 * lane16];
        const float4 y1 = vj[2 * lane16 + 1];

        float p = a0.x * b0.x + a0.y * b0.y + a0.z * b0.z + a0.w * b0.w
                + a1.x * b1.x + a1.y * b1.y + a1.z * b1.z + a1.w * b1.w
                + x0.x * y0.x + x0.y * y0.y + x0.z * y0.z + x0.w * y0.w
                + x1.x * y1.x + x1.y * y1.y + x1.z * y1.z + x1.w * y1.w;

        #pragma unroll
        for (int mk = 8; mk >= 1; mk >>= 1) p += __shfl_xor(p, mk, 64);

        if (lane16 == 0) escore[j] = __expf(p * INV_SQRT_D) * aval[k];
    }
    __syncthreads();

    // ---- phase 3: row normalize + coalesced store ----
    const float x = escore[tid];
    float s = x;
    #pragma unroll
    for (int mk = 32; mk >= 1; mk >>= 1) s += __shfl_xor(s, mk, 64);
    if (lane64 == 0) wsum[wid] = s;
    __syncthreads();
    const float denom = wsum[0] + wsum[1] + wsum[2] + wsum[3] + EPS;
    out[(size_t)row * NN + tid] = x / denom;
}

extern "C" void kernel_launch(void* const* d_in, const int* in_sizes, int n_in,
                              void* d_out, int out_size, void* d_ws, size_t ws_size,
                              hipStream_t stream) {
    const float* val = (const float*)d_in[0];
    const float* dep = (const float*)d_in[1];
    const float* adj = (const float*)d_in[2];
    float* out = (float*)d_out;

    row_kernel<<<BB * NN, 256, 0, stream>>>(val, dep, adj, out);
}